// Round 1
// baseline (1000.989 us; speedup 1.0000x reference)
//
#include <hip/hip_runtime.h>
#include <hip/hip_bf16.h>

#define B_ 64
#define S_ 1024

static constexpr size_t XW_ELEMS = 2ull * B_ * S_ * 256;   // bf16
// bi: [B][S][128] bf16 follows xw in workspace

__device__ inline float bf2f(unsigned short u) {
    union { unsigned int i; float f; } v;
    v.i = ((unsigned int)u) << 16;
    return v.f;
}

// ---------------- K1: xw[dir][b][s][g] = embed[inputs[b,s]] @ W + bias ----------------
__global__ __launch_bounds__(256) void k_xw(
    const int* __restrict__ inputs, const float* __restrict__ embed_table,
    const float* __restrict__ Wf, const float* __restrict__ bf_,
    const float* __restrict__ Wb, const float* __restrict__ bb_,
    __hip_bfloat16* __restrict__ xw) {
    const int dir = blockIdx.y;
    const float* W    = dir ? Wb  : Wf;
    const float* bias = dir ? bb_ : bf_;
    const int rowbase = blockIdx.x * 32;      // flat (b*S+s) row
    __shared__ __align__(16) float a_lds[32][128];
    const int tid = threadIdx.x;
    for (int i = tid; i < 32 * 128; i += 256) {
        int r = i >> 7, k = i & 127;
        int tok = inputs[rowbase + r];
        a_lds[r][k] = embed_table[(size_t)tok * 128 + k];
    }
    __syncthreads();
    const int g = tid;
    float acc[32];
    const float bv = bias[g];
#pragma unroll
    for (int r = 0; r < 32; ++r) acc[r] = bv;
    for (int k4 = 0; k4 < 32; ++k4) {
        const float w0 = W[(k4 * 4 + 0) * 256 + g];
        const float w1 = W[(k4 * 4 + 1) * 256 + g];
        const float w2 = W[(k4 * 4 + 2) * 256 + g];
        const float w3 = W[(k4 * 4 + 3) * 256 + g];
#pragma unroll
        for (int r = 0; r < 32; ++r) {
            const float4 av = *reinterpret_cast<const float4*>(&a_lds[r][k4 * 4]);
            acc[r] = fmaf(av.x, w0, fmaf(av.y, w1, fmaf(av.z, w2, fmaf(av.w, w3, acc[r]))));
        }
    }
    __hip_bfloat16* o = xw + ((size_t)dir * (B_ * S_) + rowbase) * 256 + g;
#pragma unroll
    for (int r = 0; r < 32; ++r) o[(size_t)r * 256] = (__hip_bfloat16)acc[r];
}

// ---------------- K2: masked LSTM recurrence, one block per (b, dir) ----------------
__global__ __launch_bounds__(256) void k_rec(
    const __hip_bfloat16* __restrict__ xw,
    const float* __restrict__ Uf, const float* __restrict__ Ub,
    const int* __restrict__ inputs,
    __hip_bfloat16* __restrict__ bi) {
    const int dir = blockIdx.x & 1;
    const int b   = blockIdx.x >> 1;
    const float* U = dir ? Ub : Uf;
    const int g = threadIdx.x;
    float ucol[64];
#pragma unroll
    for (int k = 0; k < 64; ++k) ucol[k] = U[k * 256 + g];
    __shared__ __align__(16) float h_lds[64];
    __shared__ float zact[256];
    if (g < 64) h_lds[g] = 0.f;
    float c = 0.f;
    const __hip_bfloat16* xwp = xw + ((size_t)dir * B_ + b) * S_ * 256;
    const int* inp = inputs + (size_t)b * S_;
    __hip_bfloat16* hout = bi + (size_t)b * S_ * 128 + (dir ? 64 : 0);
    __syncthreads();

    const int time0 = dir ? (S_ - 1) : 0;
    float xv_next = (float)xwp[(size_t)time0 * 256 + g];
    int   m_next  = inp[time0];
    for (int t = 0; t < S_; ++t) {
        const int time = dir ? (S_ - 1 - t) : t;
        const float xv = xv_next;
        const int   mm = m_next;
        if (t + 1 < S_) {
            const int tn = dir ? (S_ - 2 - t) : (t + 1);
            xv_next = (float)xwp[(size_t)tn * 256 + g];
            m_next  = inp[tn];
        }
        float z0 = 0.f, z1 = 0.f, z2 = 0.f, z3 = 0.f;
#pragma unroll
        for (int k = 0; k < 64; k += 4) {
            const float4 hv = *reinterpret_cast<const float4*>(&h_lds[k]);
            z0 = fmaf(hv.x, ucol[k + 0], z0);
            z1 = fmaf(hv.y, ucol[k + 1], z1);
            z2 = fmaf(hv.z, ucol[k + 2], z2);
            z3 = fmaf(hv.w, ucol[k + 3], z3);
        }
        float z = xv + ((z0 + z1) + (z2 + z3));
        float a;
        if ((g >> 6) == 2) {                 // cell gate -> tanh
            float zc = fminf(fmaxf(z, -15.f), 15.f);
            float e  = __expf(2.f * zc);
            a = (e - 1.f) / (e + 1.f);
        } else {                             // i, f, o -> sigmoid
            a = 1.f / (1.f + __expf(-z));
        }
        zact[g] = a;
        __syncthreads();                     // (A) zact ready, h reads done
        if (g < 64) {
            const float iv = zact[g], fv = zact[64 + g], gv = zact[128 + g], ov = zact[192 + g];
            const float c_new = fmaf(fv, c, iv * gv);
            const float cc = fminf(fmaxf(c_new, -15.f), 15.f);
            const float e2 = __expf(2.f * cc);
            const float th = (e2 - 1.f) / (e2 + 1.f);
            const float h_new = ov * th;
            const float h_old = h_lds[g];
            const float h2 = mm ? h_new : h_old;
            c = mm ? c_new : c;
            h_lds[g] = h2;
            hout[(size_t)time * 128 + g] = (__hip_bfloat16)h2;
        }
        __syncthreads();                     // (B) h updated
    }
}

// ---------------- K3: event_logits = sigmoid(bi[:, -1, :] @ Wt + bt) ----------------
__global__ __launch_bounds__(1024) void k_logits(
    const __hip_bfloat16* __restrict__ bi, const float* __restrict__ Wt,
    const float* __restrict__ bt, float* __restrict__ out) {
    const int tid = threadIdx.x;             // 0..1023
    const int b = tid >> 4, cls = tid & 15;
    const __hip_bfloat16* row = bi + ((size_t)b * S_ + (S_ - 1)) * 128;
    float acc = bt[cls];
    for (int k = 0; k < 128; ++k)
        acc = fmaf((float)row[k], Wt[k * 16 + cls], acc);
    out[tid] = 1.f / (1.f + __expf(-acc));
}

// ---------------- K4: expert-dedup einsum, direct scatter to out ----------------
// out[b,c,s,a] = sum_f feat[c,s,f] * W_arg[idx[b],f,a] + b_arg[idx[b],a]
__global__ __launch_bounds__(256) void k_args(
    const __hip_bfloat16* __restrict__ bi,
    const float* __restrict__ ev_table, const int* __restrict__ evt,
    const float* __restrict__ W_arg, const float* __restrict__ b_arg,
    float* __restrict__ out_args) {
    const int e = blockIdx.x;                // expert 0..14
    const int rowbase = blockIdx.y * 64;     // flat (c*S+s)
    const int cc = rowbase >> 10;            // c (S=1024, tile within one c)
    __shared__ float feat[64][169];          // 160 used, pad->169 (9 coprime 32)
    __shared__ __align__(16) float w[1280];  // W_arg[e]: [160][8]
    __shared__ float partial[4][64][8];
    __shared__ int   evt_l[64];
    __shared__ float bg[8];
    const int tid = threadIdx.x;
    for (int i = tid; i < 1280; i += 256) w[i] = W_arg[(size_t)e * 1280 + i];
    if (tid < 64) evt_l[tid] = evt[tid];
    if (tid < 8)  bg[tid] = b_arg[e * 8 + tid];
    // stage bi rows (bf16 -> f32)
    const ushort2* bi2 = reinterpret_cast<const ushort2*>(bi) + (size_t)rowbase * 64;
    for (int i = tid; i < 64 * 64; i += 256) {
        int r = i >> 6, k2 = i & 63;
        ushort2 v = bi2[(size_t)r * 64 + k2];
        feat[r][k2 * 2]     = bf2f(v.x);
        feat[r][k2 * 2 + 1] = bf2f(v.y);
    }
    {
        const int ie = evt[cc];
        const float* evrow = ev_table + (size_t)ie * 32;
        for (int i = tid; i < 64 * 32; i += 256) {
            int r = i >> 5, k = i & 31;
            feat[r][128 + k] = evrow[k];
        }
    }
    __syncthreads();
    const int r = tid & 63, seg = tid >> 6;  // lane == row, wave == f-segment
    float acc[8];
#pragma unroll
    for (int a = 0; a < 8; ++a) acc[a] = 0.f;
    const int f0 = seg * 40;
    for (int f = f0; f < f0 + 40; ++f) {
        const float fv = feat[r][f];
        const float4 w0 = *reinterpret_cast<const float4*>(&w[f * 8]);
        const float4 w1 = *reinterpret_cast<const float4*>(&w[f * 8 + 4]);
        acc[0] = fmaf(fv, w0.x, acc[0]);
        acc[1] = fmaf(fv, w0.y, acc[1]);
        acc[2] = fmaf(fv, w0.z, acc[2]);
        acc[3] = fmaf(fv, w0.w, acc[3]);
        acc[4] = fmaf(fv, w1.x, acc[4]);
        acc[5] = fmaf(fv, w1.y, acc[5]);
        acc[6] = fmaf(fv, w1.z, acc[6]);
        acc[7] = fmaf(fv, w1.w, acc[7]);
    }
#pragma unroll
    for (int a = 0; a < 8; ++a) partial[seg][r][a] = acc[a];
    __syncthreads();
    for (int o = tid; o < 512; o += 256) {
        const int rr = o >> 3, a = o & 7;
        const float v = bg[a] + partial[0][rr][a] + partial[1][rr][a]
                              + partial[2][rr][a] + partial[3][rr][a];
        const size_t base = ((size_t)(rowbase + rr)) * 8 + a;
        for (int b = 0; b < 64; ++b) {
            if (evt_l[b] == e)
                out_args[(size_t)b * (64ull * 1024 * 8) + base] = v;
        }
    }
}

// ---------------- K5: mask ----------------
__global__ __launch_bounds__(256) void k_mask(const int* __restrict__ inputs,
                                              float* __restrict__ om) {
    const int i = blockIdx.x * 256 + threadIdx.x;
    om[i] = (inputs[i] != 0) ? 1.f : 0.f;
}

extern "C" void kernel_launch(void* const* d_in, const int* in_sizes, int n_in,
                              void* d_out, int out_size, void* d_ws, size_t ws_size,
                              hipStream_t stream) {
    const int*   inputs = (const int*)d_in[0];
    const int*   evt    = (const int*)d_in[1];
    const float* embed  = (const float*)d_in[2];
    const float* Wf     = (const float*)d_in[3];
    const float* Uf     = (const float*)d_in[4];
    const float* bf_    = (const float*)d_in[5];
    const float* Wb     = (const float*)d_in[6];
    const float* Ub     = (const float*)d_in[7];
    const float* bb_    = (const float*)d_in[8];
    const float* evtab  = (const float*)d_in[9];
    const float* Wt     = (const float*)d_in[10];
    const float* bt     = (const float*)d_in[11];
    const float* W_arg  = (const float*)d_in[12];
    const float* b_arg  = (const float*)d_in[13];

    float* out        = (float*)d_out;
    float* out_logits = out;                          // 64*16
    float* out_args   = out + 1024;                   // 64*64*1024*8
    float* out_mask   = out + 1024 + 33554432;        // 64*1024

    __hip_bfloat16* xw = (__hip_bfloat16*)d_ws;       // 64 MiB
    __hip_bfloat16* bi = xw + XW_ELEMS;               // 16 MiB

    k_xw    <<<dim3(2048, 2), 256, 0, stream>>>(inputs, embed, Wf, bf_, Wb, bb_, xw);
    k_rec   <<<dim3(128),     256, 0, stream>>>(xw, Uf, Ub, inputs, bi);
    k_logits<<<dim3(1),      1024, 0, stream>>>(bi, Wt, bt, out_logits);
    k_args  <<<dim3(15, 1024), 256, 0, stream>>>(bi, evtab, evt, W_arg, b_arg, out_args);
    k_mask  <<<dim3(256),     256, 0, stream>>>(inputs, out_mask);
}